// Round 7
// baseline (236.235 us; speedup 1.0000x reference)
//
#include <hip/hip_runtime.h>
#include <cstdint>
#include <cstddef>

#define GEPS 1e-6f

using bf16x8 = __attribute__((ext_vector_type(8))) short;   // 8 bf16 = 4 VGPRs
using f32x4  = __attribute__((ext_vector_type(4))) float;   // MFMA C/D frag

__device__ inline ushort f2bf(float x) {
    union { float f; uint32_t u; } v; v.f = x;
    uint32_t r = (v.u + 0x7fffu + ((v.u >> 16) & 1u)) >> 16;  // RNE
    return (ushort)r;
}
__device__ inline float bf2f(ushort b) {
    union { float f; uint32_t u; } v; v.u = ((uint32_t)b) << 16;
    return v.f;
}

// async global->LDS, 16 bytes per lane. LDS dest = wave-uniform base + lane*16.
__device__ inline void gll16(const void* g, void* l) {
    __builtin_amdgcn_global_load_lds(
        (const __attribute__((address_space(1))) void*)g,
        (__attribute__((address_space(3))) void*)l, 16, 0, 0);
}

// ---------------------------------------------------------------------------
// Kernel 1: pack weights to bf16 (k TAP-MAJOR: k = tap*256 + ci) via LDS
//   transpose, + wo -> bf16.
// ---------------------------------------------------------------------------
__global__ __launch_bounds__(256) void pack_k(
    const float* __restrict__ wq, const float* __restrict__ wk,
    const float* __restrict__ wv, const float* __restrict__ wo,
    ushort* __restrict__ Wbuf, ushort* __restrict__ wo_bf)
{
    int blk = blockIdx.x, tid = threadIdx.x;
    if (blk < 768) {
        __shared__ ushort Ws[2304];
        int proj = blk >> 8, co = blk & 255;
        const float* src = ((proj == 0) ? wq : ((proj == 1) ? wk : wv)) + (size_t)co * 2304;
#pragma unroll
        for (int j = 0; j < 9; ++j) {
            int idx = j * 256 + tid;
            Ws[idx] = f2bf(src[idx]);       // coalesced fp32 read
        }
        __syncthreads();
        ushort* dst = Wbuf + (size_t)blk * 2304;
#pragma unroll
        for (int j = 0; j < 9; ++j)          // k = j*256+tid: tap=j, ci=tid
            dst[j * 256 + tid] = Ws[tid * 9 + j];   // coalesced store
        return;
    }
    int t = (blk - 768) * 256 + tid;         // 0..16383, 4 elems each
    float4 v = *(const float4*)&wo[(size_t)t * 4];
    union { uint2 u; ushort s[4]; } o;
    o.s[0] = f2bf(v.x); o.s[1] = f2bf(v.y); o.s[2] = f2bf(v.z); o.s[3] = f2bf(v.w);
    *(uint2*)&wo_bf[(size_t)t * 4] = o.u;
}

// ---------------------------------------------------------------------------
// Kernel 1b: expand relative bias into MFMA-fragment order:
//   Bx[((h*64+qt)*16+kt)*1024 + lane*16 + f*4 + r] (bf16), so attn reads two
//   coalesced uint4 per (wave, key-tile). Table reads are L2-hot (127 KB).
// ---------------------------------------------------------------------------
__global__ __launch_bounds__(256) void bx_k(const float* __restrict__ btab,
                                            ushort* __restrict__ Bx)
{
    int g = blockIdx.x * 4 + (threadIdx.x >> 6);   // tile id 0..8191
    int l = threadIdx.x & 63;
    int h = g >> 10, qt = (g >> 4) & 63, kt = g & 15;
    int quad = l >> 4, c = l & 15;
    union { uint4 v[2]; ushort s[16]; } o;
#pragma unroll
    for (int f = 0; f < 4; ++f)
#pragma unroll
        for (int r = 0; r < 4; ++r) {
            int qrow = qt * 16 + quad * 4 + r;
            int key = kt * 64 + f * 16 + c;
            int dy = (qrow >> 5) - (key >> 5) + 31;
            int dx = (qrow & 31) - (key & 31) + 31;
            o.s[f * 4 + r] = f2bf(btab[(dy * 63 + dx) * 8 + h]);
        }
    uint4* dst = (uint4*)(Bx + ((size_t)g * 64 + l) * 16);
    dst[0] = o.v[0];
    dst[1] = o.v[1];
}

// ---------------------------------------------------------------------------
// Kernel 2: im2col via LDS transpose. Block = (b, py, ci-half): 512 blocks.
// ---------------------------------------------------------------------------
__global__ __launch_bounds__(256) void im2col_k(const float* __restrict__ x,
                                                ushort* __restrict__ Ab)
{
    __shared__ __align__(16) ushort Xs[3 * 34 * 128];   // [yy][xx+1][ci_l] 25.5 KB
    int tid = threadIdx.x;
    int blk = blockIdx.x;               // b*64 + py*2 + half
    int b = blk >> 6, py = (blk >> 1) & 31, half = blk & 1;

#pragma unroll
    for (int p = tid; p < 768; p += 256) {
        int yy = p >> 8;
        int q = p & 255;
        int col = (q >> 7) ? 33 : 0;
        int ci = q & 127;
        Xs[(yy * 34 + col) * 128 + ci] = 0;
    }

#pragma unroll
    for (int it = 0; it < 12; ++it) {
        int j = it * 256 + tid;
        int ci_l = j / 24;
        int o = (j - ci_l * 24) * 4;
        int yy = o >> 5, xx = o & 31;
        int row = py - 1 + yy;
        float4 v = make_float4(0.f, 0.f, 0.f, 0.f);
        if (row >= 0 && row < 32)
            v = *(const float4*)&x[((size_t)(b * 256 + half * 128 + ci_l)) * 1024 + row * 32 + xx];
        int base = (yy * 34 + xx + 1) * 128 + ci_l;
        Xs[base + 0 * 128] = f2bf(v.x);
        Xs[base + 1 * 128] = f2bf(v.y);
        Xs[base + 2 * 128] = f2bf(v.z);
        Xs[base + 3 * 128] = f2bf(v.w);
    }
    __syncthreads();

    ushort* dst = Ab + (size_t)(b * 1024 + py * 32) * 2304;
#pragma unroll
    for (int it = 0; it < 18; ++it) {
        int idx = it * 256 + tid;       // 0..4607
        int ci8l = idx & 15;
        int tp = (idx >> 4) % 9;
        int px = idx / 144;
        int kh = tp / 3, kw = tp - kh * 3;
        uint4 p = *(const uint4*)&Xs[(kh * 34 + px + kw) * 128 + ci8l * 8];
        *(uint4*)&dst[(size_t)(px * 288 + tp * 32 + half * 16 + ci8l) * 8] = p;
    }
}

// ---------------------------------------------------------------------------
// Kernel 3/7: bf16 GEMM  C[M,N] = A[M,K] * B[N,K]^T, 128x128 tile, BK=64,
//   split-K via blockIdx.z, PLAIN-STORE partials.
//   mode 0 (conv): store fp32 partial to Cpart + z*M*N
//   mode 1 (out-proj, gridDim.z==1): store fp32 d_out[b][o][px] = C + bias[o]
// ---------------------------------------------------------------------------
__global__ __launch_bounds__(256, 3) void gemm_bt(
    const ushort* __restrict__ A, const ushort* __restrict__ B,
    int M, int N, int K,
    float* __restrict__ Cpart,
    float* __restrict__ Cout, const float* __restrict__ bias, int mode)
{
    __shared__ __align__(16) ushort As[128 * 64];
    __shared__ __align__(16) ushort Bs[128 * 64];
    int tid = threadIdx.x;
    int mbase = blockIdx.x * 128, nbase = blockIdx.y * 128;
    int kspan = K / gridDim.z;
    int k0 = blockIdx.z * kspan;
    int wave = tid >> 6, lane = tid & 63;
    int wm = wave & 1, wn = wave >> 1;
    int quad = lane >> 4, c = lane & 15;

    int row_s = tid >> 3;               // 0..31 staging row within chunk
    int cc8 = (tid & 7) ^ (row_s & 7);  // swizzled global column-block
    ushort* ldsA = As + wave * 512;     // wave-uniform dest base (+lane*16B)
    ushort* ldsB = Bs + wave * 512;

    f32x4 acc[4][4];
#pragma unroll
    for (int i = 0; i < 4; ++i)
#pragma unroll
        for (int j = 0; j < 4; ++j) acc[i][j] = (f32x4){0.f, 0.f, 0.f, 0.f};

    for (int kb = k0; kb < k0 + kspan; kb += 64) {
        __syncthreads();
#pragma unroll
        for (int R = 0; R < 4; ++R) {
            int row = R * 32 + row_s;
            gll16(A + (size_t)(mbase + row) * K + kb + cc8 * 8,
                  ldsA + R * 2048);
            gll16(B + (size_t)(nbase + row) * K + kb + cc8 * 8,
                  ldsB + R * 2048);
        }
        __syncthreads();
#pragma unroll
        for (int kq = 0; kq < 2; ++kq) {
            bf16x8 af[4], bfr[4];
            int sw = ((kq * 4 + quad) ^ (c & 7)) * 8;
#pragma unroll
            for (int i = 0; i < 4; ++i) {
                af[i]  = *(const bf16x8*)&As[(wm * 64 + i * 16 + c) * 64 + sw];
                bfr[i] = *(const bf16x8*)&Bs[(wn * 64 + i * 16 + c) * 64 + sw];
            }
#pragma unroll
            for (int i = 0; i < 4; ++i)
#pragma unroll
                for (int j = 0; j < 4; ++j)
                    acc[i][j] = __builtin_amdgcn_mfma_f32_16x16x32_bf16(
                        af[i], bfr[j], acc[i][j], 0, 0, 0);
        }
    }

    if (mode == 0) {
        float* Cp = Cpart + (size_t)blockIdx.z * M * N;
#pragma unroll
        for (int i = 0; i < 4; ++i) {
            int mrow = mbase + wm * 64 + i * 16 + quad * 4;
#pragma unroll
            for (int j = 0; j < 4; ++j) {
                int ncol = nbase + wn * 64 + j * 16 + c;
#pragma unroll
                for (int r = 0; r < 4; ++r)
                    Cp[(size_t)(mrow + r) * N + ncol] = acc[i][j][r];
            }
        }
    } else {
#pragma unroll
        for (int i = 0; i < 4; ++i) {
            int mrow0 = mbase + wm * 64 + i * 16 + quad * 4;
#pragma unroll
            for (int j = 0; j < 4; ++j) {
                int ncol = nbase + wn * 64 + j * 16 + c;
                int bb = ncol >> 10, px = ncol & 1023;
#pragma unroll
                for (int r = 0; r < 4; ++r) {
                    int o = mrow0 + r;
                    Cout[((size_t)bb * 256 + o) * 1024 + px] = acc[i][j][r] + bias[o];
                }
            }
        }
    }
}

// ---------------------------------------------------------------------------
// Kernel 4: stats stage 1 — atomic-free partials.
// ---------------------------------------------------------------------------
__global__ __launch_bounds__(256) void stats1_k(const float* __restrict__ P0,
                                                const float* __restrict__ P1,
                                                float2* __restrict__ part)
{
    int t = blockIdx.x * 256 + threadIdx.x;     // 786432 threads x 8 elems
    size_t base = (size_t)t * 8;
    float4 a0 = *(const float4*)&P0[base];
    float4 a1 = *(const float4*)&P0[base + 4];
    float4 c0 = *(const float4*)&P1[base];
    float4 c1 = *(const float4*)&P1[base + 4];
    float v[8] = {a0.x + c0.x, a0.y + c0.y, a0.z + c0.z, a0.w + c0.w,
                  a1.x + c1.x, a1.y + c1.y, a1.z + c1.z, a1.w + c1.w};
    float s1 = 0.f, s2 = 0.f;
#pragma unroll
    for (int e = 0; e < 8; ++e) { s1 += v[e]; s2 += v[e] * v[e]; }
#pragma unroll
    for (int mk = 1; mk < 32; mk <<= 1) {
        s1 += __shfl_xor(s1, mk, 64);
        s2 += __shfl_xor(s2, mk, 64);
    }
    if ((threadIdx.x & 31) == 0) {
        int gg = t >> 5;                // group = one 256-elem (proj,m) segment
        int m = gg / 3;
        int proj = gg - m * 3;
        int b = m >> 10, slot = m & 1023;
        part[(proj * 8 + b) * 1024 + slot] = make_float2(s1, s2);
    }
}

// ---------------------------------------------------------------------------
// Kernel 4b: stats stage 2 — 48 blocks, each reduces 1024 float2 partials.
// ---------------------------------------------------------------------------
__global__ __launch_bounds__(256) void stats2_k(const float2* __restrict__ part,
                                                float* __restrict__ stats)
{
    __shared__ float w1[4], w2[4];
    int s = blockIdx.x, tid = threadIdx.x;
    float s1 = 0.f, s2 = 0.f;
#pragma unroll
    for (int i = 0; i < 4; ++i) {
        float2 v = part[(size_t)s * 1024 + tid * 4 + i];
        s1 += v.x; s2 += v.y;
    }
#pragma unroll
    for (int mk = 1; mk < 64; mk <<= 1) {
        s1 += __shfl_xor(s1, mk, 64);
        s2 += __shfl_xor(s2, mk, 64);
    }
    if ((tid & 63) == 0) { w1[tid >> 6] = s1; w2[tid >> 6] = s2; }
    __syncthreads();
    if (tid == 0) {
        stats[s * 2 + 0] = w1[0] + w1[1] + w1[2] + w1[3];
        stats[s * 2 + 1] = w2[0] + w2[1] + w2[2] + w2[3];
    }
}

// ---------------------------------------------------------------------------
// Kernel 5: GroupNorm(1) + exact GELU + head reshape; sums split-K partials.
//   q/k -> [b][h][n][d]; V -> fragment order Vx[bh][kca][half][lane][8] so
//   attn's PV B-frag loads are fully coalesced.
// ---------------------------------------------------------------------------
__global__ void gn_k(const float* __restrict__ P0, const float* __restrict__ P1,
                     const float* __restrict__ stats,
                     const float* __restrict__ gq, const float* __restrict__ bq,
                     const float* __restrict__ gk, const float* __restrict__ bk,
                     const float* __restrict__ gv, const float* __restrict__ bv,
                     ushort* __restrict__ qb, ushort* __restrict__ kb2,
                     ushort* __restrict__ vx)
{
    int t = blockIdx.x * 256 + threadIdx.x;     // 8192 * 96 threads
    int m = t / 96;
    int nn = (t - m * 96) * 8;
    int proj = nn >> 8, co = nn & 255;
    int b = m >> 10, px = m & 1023;
    float s1 = stats[(proj * 8 + b) * 2 + 0];
    float s2 = stats[(proj * 8 + b) * 2 + 1];
    const float Ninv = 1.f / 262144.f;
    float mu = s1 * Ninv;
    float var = fmaxf(s2 * Ninv - mu * mu, 0.f);
    float rsig = rsqrtf(var + GEPS);
    const float* gam = (proj == 0) ? gq : ((proj == 1) ? gk : gv);
    const float* bet = (proj == 0) ? bq : ((proj == 1) ? bk : bv);

    size_t base = (size_t)m * 768 + nn;
    float4 a0 = *(const float4*)&P0[base];
    float4 a1 = *(const float4*)&P0[base + 4];
    float4 c0 = *(const float4*)&P1[base];
    float4 c1 = *(const float4*)&P1[base + 4];
    float xv[8] = {a0.x + c0.x, a0.y + c0.y, a0.z + c0.z, a0.w + c0.w,
                   a1.x + c1.x, a1.y + c1.y, a1.z + c1.z, a1.w + c1.w};
    union { uint4 v; ushort s[8]; } outp;
#pragma unroll
    for (int e = 0; e < 8; ++e) {
        int cc = co + e;
        float xn = (xv[e] - mu) * rsig * gam[cc] + bet[cc];
        float ge = 0.5f * xn * (1.f + erff(xn * 0.70710678118654752f));
        outp.s[e] = f2bf(ge);
    }
    int h = co >> 5, d = co & 31;
    if (proj == 0) {
        *(uint4*)(qb + ((((size_t)b * 8 + h) * 1024 + px) * 32 + d)) = outp.v;
    } else if (proj == 1) {
        *(uint4*)(kb2 + ((((size_t)b * 8 + h) * 1024 + px) * 32 + d)) = outp.v;
    } else {
        // Vx[bh][kca=px>>5][half=d>>4][lane=quad*16+(d&15)][j=px&7]
        ushort* vb = vx + ((size_t)b * 8 + h) * 32768;
        int kca = px >> 5, quad = (px >> 3) & 3, j = px & 7;
#pragma unroll
        for (int e = 0; e < 8; ++e) {
            int dd = d + e;
            vb[(((kca * 2 + (dd >> 4)) * 64) + quad * 16 + (dd & 15)) * 8 + j] = outp.s[e];
        }
    }
}

// ---------------------------------------------------------------------------
// Kernel 6: fused attention. Bias from fragment-ordered Bx (2 coalesced
//   uint4 loads per key-tile); V from fragment-ordered Vx (coalesced 16B/lane
//   loads). No online-softmax (scores bounded); l reduced once at the end.
// ---------------------------------------------------------------------------
__global__ __launch_bounds__(256, 2) void attn_k(
    const ushort* __restrict__ qb, const ushort* __restrict__ kb,
    const ushort* __restrict__ vx, const ushort* __restrict__ Bx,
    ushort* __restrict__ attnout)
{
    __shared__ __align__(16) ushort Pl[4 * 16 * 72];
    int tid = threadIdx.x, wave = tid >> 6, lane = tid & 63;
    int quad = lane >> 4, c = lane & 15;
    int bh = blockIdx.y;               // b*8 + h
    int h = bh & 7, b = bh >> 3;
    int qbase = blockIdx.x * 64 + wave * 16;

    const ushort* Q  = qb + (size_t)bh * 1024 * 32;
    const ushort* Kp = kb + (size_t)bh * 1024 * 32;
    const ushort* Vb = vx + (size_t)bh * 32768;
    // Bx tile base for this (h, qt): tiles are ((h*64+qt)*16 + kt)
    const ushort* bxp = Bx + (((size_t)(h * 64 + (qbase >> 4)) * 16) * 64 + lane) * 16;
    ushort* Pw = Pl + wave * 16 * 72;

    bf16x8 qf = *(const bf16x8*)&Q[(qbase + c) * 32 + quad * 8];

    float l_[4] = {0.f, 0.f, 0.f, 0.f};
    f32x4 Of0 = {0.f, 0.f, 0.f, 0.f}, Of1 = {0.f, 0.f, 0.f, 0.f};

    for (int kb64 = 0; kb64 < 1024; kb64 += 64) {
        f32x4 S[4];
        f32x4 zf = {0.f, 0.f, 0.f, 0.f};
#pragma unroll
        for (int f = 0; f < 4; ++f) {
            bf16x8 kf = *(const bf16x8*)&Kp[(kb64 + f * 16 + c) * 32 + quad * 8];
            S[f] = __builtin_amdgcn_mfma_f32_16x16x32_bf16(qf, kf, zf, 0, 0, 0);
        }
        // fragment-ordered bias: 32 B per lane, coalesced
        union { uint4 v[2]; ushort s[16]; } bu;
        const uint4* bsrc = (const uint4*)(bxp + (size_t)(kb64 >> 6) * 1024);
        bu.v[0] = bsrc[0];
        bu.v[1] = bsrc[1];
#pragma unroll
        for (int f = 0; f < 4; ++f)
#pragma unroll
            for (int r = 0; r < 4; ++r) {
                float p = __expf(S[f][r] + bf2f(bu.s[f * 4 + r]));
                S[f][r] = p;
                l_[r] += p;
            }
        // P (C-layout) -> LDS -> A-layout; per-wave slice, no barrier needed
#pragma unroll
        for (int f = 0; f < 4; ++f)
#pragma unroll
            for (int r = 0; r < 4; ++r)
                Pw[(quad * 4 + r) * 72 + f * 16 + c] = f2bf(S[f][r]);
#pragma unroll
        for (int kc = 0; kc < 2; ++kc) {
            int kca = (kb64 >> 5) + kc;
            bf16x8 pf = *(const bf16x8*)&Pw[c * 72 + kc * 32 + quad * 8];
            bf16x8 vf0 = *(const bf16x8*)&Vb[((kca * 2 + 0) * 64 + lane) * 8];
            Of0 = __builtin_amdgcn_mfma_f32_16x16x32_bf16(pf, vf0, Of0, 0, 0, 0);
            bf16x8 vf1 = *(const bf16x8*)&Vb[((kca * 2 + 1) * 64 + lane) * 8];
            Of1 = __builtin_amdgcn_mfma_f32_16x16x32_bf16(pf, vf1, Of1, 0, 0, 0);
        }
    }
#pragma unroll
    for (int r = 0; r < 4; ++r) {
        float l = l_[r];
        l += __shfl_xor(l, 1, 64);
        l += __shfl_xor(l, 2, 64);
        l += __shfl_xor(l, 4, 64);
        l += __shfl_xor(l, 8, 64);
        float inv = 1.f / l;
        int qr = qbase + quad * 4 + r;
        size_t base = ((size_t)b * 1024 + qr) * 256 + h * 32;
        attnout[base + c]      = f2bf(Of0[r] * inv);
        attnout[base + 16 + c] = f2bf(Of1[r] * inv);
    }
}

// ---------------------------------------------------------------------------
extern "C" void kernel_launch(void* const* d_in, const int* in_sizes, int n_in,
                              void* d_out, int out_size, void* d_ws, size_t ws_size,
                              hipStream_t stream)
{
    const float* x    = (const float*)d_in[0];
    const float* wq   = (const float*)d_in[1];
    const float* wk   = (const float*)d_in[2];
    const float* wv   = (const float*)d_in[3];
    const float* gq   = (const float*)d_in[4];
    const float* bq   = (const float*)d_in[5];
    const float* gk   = (const float*)d_in[6];
    const float* bk   = (const float*)d_in[7];
    const float* gv   = (const float*)d_in[8];
    const float* bv   = (const float*)d_in[9];
    const float* btab = (const float*)d_in[10];
    const float* wo   = (const float*)d_in[11];
    const float* bo   = (const float*)d_in[12];
    float* out = (float*)d_out;

    char* w = (char*)d_ws;
    size_t off = 0;
    auto alloc = [&](size_t bytes) -> char* {
        char* p = w + off;
        off += (bytes + 255) & ~(size_t)255;
        return p;
    };
    ushort* Abuf    = (ushort*)alloc(8192ull * 2304 * 2);   // im2col patches (36.9 MB)
    ushort* Wbuf    = (ushort*)alloc(768ull * 2304 * 2);    // concat conv weights
    ushort* wo_bf   = (ushort*)alloc(65536ull * 2);         // out-proj weight
    float*  P0      = (float*)alloc(8192ull * 768 * 4);     // split-K partial 0
    float*  P1      = (float*)alloc(8192ull * 768 * 4);     // split-K partial 1
    float2* part    = (float2*)alloc(48ull * 1024 * 8);     // stats partials
    float*  stats   = (float*)alloc(384);                   // [proj][b][sum,sumsq]
    // aliases into Abuf (dead after the conv GEMM; stream-ordered):
    ushort* qb      = (ushort*)Abuf;                        // 4 MB
    ushort* kb2     = qb  + 8ull * 8 * 1024 * 32;           // 4 MB
    ushort* vx      = kb2 + 8ull * 8 * 1024 * 32;           // 4 MB (fragment order)
    ushort* attnout = vx  + 8ull * 8 * 32 * 1024;           // 4 MB
    ushort* Bx      = attnout + 8192ull * 256;              // 16.7 MB (ends 32.7 MB < 36.9)

    pack_k<<<832, 256, 0, stream>>>(wq, wk, wv, wo, Wbuf, wo_bf);
    im2col_k<<<512, 256, 0, stream>>>(x, Abuf);
    gemm_bt<<<dim3(64, 6, 2), 256, 0, stream>>>(Abuf, Wbuf, 8192, 768, 2304,
                                                P0, nullptr, nullptr, 0);
    bx_k<<<2048, 256, 0, stream>>>(btab, Bx);
    stats1_k<<<3072, 256, 0, stream>>>(P0, P1, part);
    stats2_k<<<48, 256, 0, stream>>>(part, stats);
    gn_k<<<3072, 256, 0, stream>>>(P0, P1, stats, gq, bq, gk, bk, gv, bv,
                                   qb, kb2, vx);
    attn_k<<<dim3(16, 64), 256, 0, stream>>>(qb, kb2, vx, Bx, attnout);
    gemm_bt<<<dim3(2, 64, 1), 256, 0, stream>>>(wo_bf, attnout, 256, 8192, 256,
                                                nullptr, out, bo, 1);
}

// Round 9
// 231.212 us; speedup vs baseline: 1.0217x; 1.0217x over previous
//
#include <hip/hip_runtime.h>
#include <cstdint>
#include <cstddef>

#define GEPS 1e-6f

using bf16x8 = __attribute__((ext_vector_type(8))) short;   // 8 bf16 = 4 VGPRs
using f32x4  = __attribute__((ext_vector_type(4))) float;   // MFMA C/D frag

__device__ inline ushort f2bf(float x) {
    union { float f; uint32_t u; } v; v.f = x;
    uint32_t r = (v.u + 0x7fffu + ((v.u >> 16) & 1u)) >> 16;  // RNE
    return (ushort)r;
}
__device__ inline float bf2f(ushort b) {
    union { float f; uint32_t u; } v; v.u = ((uint32_t)b) << 16;
    return v.f;
}

// async global->LDS, 16 bytes per lane. LDS dest = wave-uniform base + lane*16.
__device__ inline void gll16(const void* g, void* l) {
    __builtin_amdgcn_global_load_lds(
        (const __attribute__((address_space(1))) void*)g,
        (__attribute__((address_space(3))) void*)l, 16, 0, 0);
}

// ---------------------------------------------------------------------------
// Kernel 1: merged preprocessing (one launch). NOTE: Bx has a DEDICATED
//   workspace region (round-8 bug: it aliased Abuf while im2col blocks in
//   the SAME kernel were writing Abuf -> race).
//   blocks 0..511     : im2col via LDS transpose (b, py, ci-half)
//   blocks 512..1279  : conv weights -> bf16, k TAP-MAJOR (k = tap*256+ci)
//   blocks 1280..1343 : wo -> bf16
//   blocks 1344..3391 : bias table -> MFMA-fragment-ordered Bx (bf16)
// ---------------------------------------------------------------------------
__global__ __launch_bounds__(256) void prep_k(
    const float* __restrict__ x,
    const float* __restrict__ wq, const float* __restrict__ wk,
    const float* __restrict__ wv, const float* __restrict__ wo,
    const float* __restrict__ btab,
    ushort* __restrict__ Ab, ushort* __restrict__ Wbuf,
    ushort* __restrict__ wo_bf, ushort* __restrict__ Bx)
{
    __shared__ __align__(16) ushort Xs[3 * 34 * 128];   // 25.5 KB (max use)
    int tid = threadIdx.x;
    int blk = blockIdx.x;

    if (blk < 512) {
        // ---- im2col ----
        int b = blk >> 6, py = (blk >> 1) & 31, half = blk & 1;
#pragma unroll
        for (int p = tid; p < 768; p += 256) {
            int yy = p >> 8;
            int q = p & 255;
            int col = (q >> 7) ? 33 : 0;
            int ci = q & 127;
            Xs[(yy * 34 + col) * 128 + ci] = 0;
        }
#pragma unroll
        for (int it = 0; it < 12; ++it) {
            int j = it * 256 + tid;
            int ci_l = j / 24;
            int o = (j - ci_l * 24) * 4;
            int yy = o >> 5, xx = o & 31;
            int row = py - 1 + yy;
            float4 v = make_float4(0.f, 0.f, 0.f, 0.f);
            if (row >= 0 && row < 32)
                v = *(const float4*)&x[((size_t)(b * 256 + half * 128 + ci_l)) * 1024 + row * 32 + xx];
            int base = (yy * 34 + xx + 1) * 128 + ci_l;
            Xs[base + 0 * 128] = f2bf(v.x);
            Xs[base + 1 * 128] = f2bf(v.y);
            Xs[base + 2 * 128] = f2bf(v.z);
            Xs[base + 3 * 128] = f2bf(v.w);
        }
        __syncthreads();
        ushort* dst = Ab + (size_t)(b * 1024 + py * 32) * 2304;
#pragma unroll
        for (int it = 0; it < 18; ++it) {
            int idx = it * 256 + tid;       // 0..4607
            int ci8l = idx & 15;
            int tp = (idx >> 4) % 9;
            int px = idx / 144;
            int kh = tp / 3, kw = tp - kh * 3;
            uint4 p = *(const uint4*)&Xs[(kh * 34 + px + kw) * 128 + ci8l * 8];
            *(uint4*)&dst[(size_t)(px * 288 + tp * 32 + half * 16 + ci8l) * 8] = p;
        }
        return;
    }
    if (blk < 1280) {
        // ---- conv weight pack (LDS transpose) ----
        int wrow = blk - 512;               // 0..767
        int proj = wrow >> 8, co = wrow & 255;
        const float* src = ((proj == 0) ? wq : ((proj == 1) ? wk : wv)) + (size_t)co * 2304;
#pragma unroll
        for (int j = 0; j < 9; ++j) {
            int idx = j * 256 + tid;
            Xs[idx] = f2bf(src[idx]);       // coalesced fp32 read
        }
        __syncthreads();
        ushort* dst = Wbuf + (size_t)wrow * 2304;
#pragma unroll
        for (int j = 0; j < 9; ++j)          // k = j*256+tid: tap=j, ci=tid
            dst[j * 256 + tid] = Xs[tid * 9 + j];   // coalesced store
        return;
    }
    if (blk < 1344) {
        // ---- wo pack ----
        int t = (blk - 1280) * 256 + tid;    // 0..16383, 4 elems each
        float4 v = *(const float4*)&wo[(size_t)t * 4];
        union { uint2 u; ushort s[4]; } o;
        o.s[0] = f2bf(v.x); o.s[1] = f2bf(v.y); o.s[2] = f2bf(v.z); o.s[3] = f2bf(v.w);
        *(uint2*)&wo_bf[(size_t)t * 4] = o.u;
        return;
    }
    // ---- Bx expansion ----
    int g = (blk - 1344) * 4 + (tid >> 6);   // tile id 0..8191
    int l = tid & 63;
    int h = g >> 10, qt = (g >> 4) & 63, kt = g & 15;
    int quad = l >> 4, c = l & 15;
    union { uint4 v[2]; ushort s[16]; } o;
#pragma unroll
    for (int f = 0; f < 4; ++f)
#pragma unroll
        for (int r = 0; r < 4; ++r) {
            int qrow = qt * 16 + quad * 4 + r;
            int key = kt * 64 + f * 16 + c;
            int dy = (qrow >> 5) - (key >> 5) + 31;
            int dx = (qrow & 31) - (key & 31) + 31;
            o.s[f * 4 + r] = f2bf(btab[(dy * 63 + dx) * 8 + h]);
        }
    uint4* dst = (uint4*)(Bx + ((size_t)g * 64 + l) * 16);
    dst[0] = o.v[0];
    dst[1] = o.v[1];
}

// ---------------------------------------------------------------------------
// Kernel 2/8: bf16 GEMM  C[M,N] = A[M,K] * B[N,K]^T, 128x128 tile, BK=64,
//   split-K via blockIdx.z, PLAIN-STORE partials.
//   mode 0 (conv): store fp32 partial to Cpart + z*M*N
//   mode 1 (out-proj, gridDim.z==1): store fp32 d_out[b][o][px] = C + bias[o]
// ---------------------------------------------------------------------------
__global__ __launch_bounds__(256, 3) void gemm_bt(
    const ushort* __restrict__ A, const ushort* __restrict__ B,
    int M, int N, int K,
    float* __restrict__ Cpart,
    float* __restrict__ Cout, const float* __restrict__ bias, int mode)
{
    __shared__ __align__(16) ushort As[128 * 64];
    __shared__ __align__(16) ushort Bs[128 * 64];
    int tid = threadIdx.x;
    int mbase = blockIdx.x * 128, nbase = blockIdx.y * 128;
    int kspan = K / gridDim.z;
    int k0 = blockIdx.z * kspan;
    int wave = tid >> 6, lane = tid & 63;
    int wm = wave & 1, wn = wave >> 1;
    int quad = lane >> 4, c = lane & 15;

    int row_s = tid >> 3;               // 0..31 staging row within chunk
    int cc8 = (tid & 7) ^ (row_s & 7);  // swizzled global column-block
    ushort* ldsA = As + wave * 512;     // wave-uniform dest base (+lane*16B)
    ushort* ldsB = Bs + wave * 512;

    f32x4 acc[4][4];
#pragma unroll
    for (int i = 0; i < 4; ++i)
#pragma unroll
        for (int j = 0; j < 4; ++j) acc[i][j] = (f32x4){0.f, 0.f, 0.f, 0.f};

    for (int kb = k0; kb < k0 + kspan; kb += 64) {
        __syncthreads();
#pragma unroll
        for (int R = 0; R < 4; ++R) {
            int row = R * 32 + row_s;
            gll16(A + (size_t)(mbase + row) * K + kb + cc8 * 8,
                  ldsA + R * 2048);
            gll16(B + (size_t)(nbase + row) * K + kb + cc8 * 8,
                  ldsB + R * 2048);
        }
        __syncthreads();
#pragma unroll
        for (int kq = 0; kq < 2; ++kq) {
            bf16x8 af[4], bfr[4];
            int sw = ((kq * 4 + quad) ^ (c & 7)) * 8;
#pragma unroll
            for (int i = 0; i < 4; ++i) {
                af[i]  = *(const bf16x8*)&As[(wm * 64 + i * 16 + c) * 64 + sw];
                bfr[i] = *(const bf16x8*)&Bs[(wn * 64 + i * 16 + c) * 64 + sw];
            }
#pragma unroll
            for (int i = 0; i < 4; ++i)
#pragma unroll
                for (int j = 0; j < 4; ++j)
                    acc[i][j] = __builtin_amdgcn_mfma_f32_16x16x32_bf16(
                        af[i], bfr[j], acc[i][j], 0, 0, 0);
        }
    }

    if (mode == 0) {
        float* Cp = Cpart + (size_t)blockIdx.z * M * N;
#pragma unroll
        for (int i = 0; i < 4; ++i) {
            int mrow = mbase + wm * 64 + i * 16 + quad * 4;
#pragma unroll
            for (int j = 0; j < 4; ++j) {
                int ncol = nbase + wn * 64 + j * 16 + c;
#pragma unroll
                for (int r = 0; r < 4; ++r)
                    Cp[(size_t)(mrow + r) * N + ncol] = acc[i][j][r];
            }
        }
    } else {
#pragma unroll
        for (int i = 0; i < 4; ++i) {
            int mrow0 = mbase + wm * 64 + i * 16 + quad * 4;
#pragma unroll
            for (int j = 0; j < 4; ++j) {
                int ncol = nbase + wn * 64 + j * 16 + c;
                int bb = ncol >> 10, px = ncol & 1023;
#pragma unroll
                for (int r = 0; r < 4; ++r) {
                    int o = mrow0 + r;
                    Cout[((size_t)bb * 256 + o) * 1024 + px] = acc[i][j][r] + bias[o];
                }
            }
        }
    }
}

// ---------------------------------------------------------------------------
// Kernel 3: stats stage 1 — atomic-free partials.
// ---------------------------------------------------------------------------
__global__ __launch_bounds__(256) void stats1_k(const float* __restrict__ P0,
                                                const float* __restrict__ P1,
                                                float2* __restrict__ part)
{
    int t = blockIdx.x * 256 + threadIdx.x;     // 786432 threads x 8 elems
    size_t base = (size_t)t * 8;
    float4 a0 = *(const float4*)&P0[base];
    float4 a1 = *(const float4*)&P0[base + 4];
    float4 c0 = *(const float4*)&P1[base];
    float4 c1 = *(const float4*)&P1[base + 4];
    float v[8] = {a0.x + c0.x, a0.y + c0.y, a0.z + c0.z, a0.w + c0.w,
                  a1.x + c1.x, a1.y + c1.y, a1.z + c1.z, a1.w + c1.w};
    float s1 = 0.f, s2 = 0.f;
#pragma unroll
    for (int e = 0; e < 8; ++e) { s1 += v[e]; s2 += v[e] * v[e]; }
#pragma unroll
    for (int mk = 1; mk < 32; mk <<= 1) {
        s1 += __shfl_xor(s1, mk, 64);
        s2 += __shfl_xor(s2, mk, 64);
    }
    if ((threadIdx.x & 31) == 0) {
        int gg = t >> 5;                // group = one 256-elem (proj,m) segment
        int m = gg / 3;
        int proj = gg - m * 3;
        int b = m >> 10, slot = m & 1023;
        part[(proj * 8 + b) * 1024 + slot] = make_float2(s1, s2);
    }
}

// ---------------------------------------------------------------------------
// Kernel 3b: stats stage 2 — 48 blocks, each reduces 1024 float2 partials.
// ---------------------------------------------------------------------------
__global__ __launch_bounds__(256) void stats2_k(const float2* __restrict__ part,
                                                float* __restrict__ stats)
{
    __shared__ float w1[4], w2[4];
    int s = blockIdx.x, tid = threadIdx.x;
    float s1 = 0.f, s2 = 0.f;
#pragma unroll
    for (int i = 0; i < 4; ++i) {
        float2 v = part[(size_t)s * 1024 + tid * 4 + i];
        s1 += v.x; s2 += v.y;
    }
#pragma unroll
    for (int mk = 1; mk < 64; mk <<= 1) {
        s1 += __shfl_xor(s1, mk, 64);
        s2 += __shfl_xor(s2, mk, 64);
    }
    if ((tid & 63) == 0) { w1[tid >> 6] = s1; w2[tid >> 6] = s2; }
    __syncthreads();
    if (tid == 0) {
        stats[s * 2 + 0] = w1[0] + w1[1] + w1[2] + w1[3];
        stats[s * 2 + 1] = w2[0] + w2[1] + w2[2] + w2[3];
    }
}

// ---------------------------------------------------------------------------
// Kernel 4: GroupNorm(1) + exact GELU + head reshape; sums split-K partials.
//   q/k -> [b][h][n][d]; V -> fragment order Vx so PV B-frags are coalesced.
// ---------------------------------------------------------------------------
__global__ void gn_k(const float* __restrict__ P0, const float* __restrict__ P1,
                     const float* __restrict__ stats,
                     const float* __restrict__ gq, const float* __restrict__ bq,
                     const float* __restrict__ gk, const float* __restrict__ bk,
                     const float* __restrict__ gv, const float* __restrict__ bv,
                     ushort* __restrict__ qb, ushort* __restrict__ kb2,
                     ushort* __restrict__ vx)
{
    int t = blockIdx.x * 256 + threadIdx.x;     // 8192 * 96 threads
    int m = t / 96;
    int nn = (t - m * 96) * 8;
    int proj = nn >> 8, co = nn & 255;
    int b = m >> 10, px = m & 1023;
    float s1 = stats[(proj * 8 + b) * 2 + 0];
    float s2 = stats[(proj * 8 + b) * 2 + 1];
    const float Ninv = 1.f / 262144.f;
    float mu = s1 * Ninv;
    float var = fmaxf(s2 * Ninv - mu * mu, 0.f);
    float rsig = rsqrtf(var + GEPS);
    const float* gam = (proj == 0) ? gq : ((proj == 1) ? gk : gv);
    const float* bet = (proj == 0) ? bq : ((proj == 1) ? bk : bv);

    size_t base = (size_t)m * 768 + nn;
    float4 a0 = *(const float4*)&P0[base];
    float4 a1 = *(const float4*)&P0[base + 4];
    float4 c0 = *(const float4*)&P1[base];
    float4 c1 = *(const float4*)&P1[base + 4];
    float xv[8] = {a0.x + c0.x, a0.y + c0.y, a0.z + c0.z, a0.w + c0.w,
                   a1.x + c1.x, a1.y + c1.y, a1.z + c1.z, a1.w + c1.w};
    union { uint4 v; ushort s[8]; } outp;
#pragma unroll
    for (int e = 0; e < 8; ++e) {
        int cc = co + e;
        float xn = (xv[e] - mu) * rsig * gam[cc] + bet[cc];
        float ge = 0.5f * xn * (1.f + erff(xn * 0.70710678118654752f));
        outp.s[e] = f2bf(ge);
    }
    int h = co >> 5, d = co & 31;
    if (proj == 0) {
        *(uint4*)(qb + ((((size_t)b * 8 + h) * 1024 + px) * 32 + d)) = outp.v;
    } else if (proj == 1) {
        *(uint4*)(kb2 + ((((size_t)b * 8 + h) * 1024 + px) * 32 + d)) = outp.v;
    } else {
        // Vx[bh][kca=px>>5][half=d>>4][lane=quad*16+(d&15)][j=px&7]
        ushort* vb = vx + ((size_t)b * 8 + h) * 32768;
        int kca = px >> 5, quad = (px >> 3) & 3, j = px & 7;
#pragma unroll
        for (int e = 0; e < 8; ++e) {
            int dd = d + e;
            vb[(((kca * 2 + (dd >> 4)) * 64) + quad * 16 + (dd & 15)) * 8 + j] = outp.s[e];
        }
    }
}

// ---------------------------------------------------------------------------
// Kernel 5: fused attention, KEY-SPLIT z=2 (2048 blocks -> ~8 blocks/CU,
//   up to 32 waves/CU to hide the serial QK->exp->LDS->PV chain).
//   Writes UNNORMALIZED fp32 partials O and l; combine_k finishes.
// ---------------------------------------------------------------------------
__global__ __launch_bounds__(256, 8) void attn_k(
    const ushort* __restrict__ qb, const ushort* __restrict__ kb,
    const ushort* __restrict__ vx, const ushort* __restrict__ Bx,
    float* __restrict__ Opart, float* __restrict__ lpart)
{
    __shared__ __align__(16) ushort Pl[4 * 16 * 72];
    int tid = threadIdx.x, wave = tid >> 6, lane = tid & 63;
    int quad = lane >> 4, c = lane & 15;
    int bh = blockIdx.y;               // b*8 + h
    int h = bh & 7;
    int z = blockIdx.z;
    int qbase = blockIdx.x * 64 + wave * 16;

    const ushort* Q  = qb + (size_t)bh * 1024 * 32;
    const ushort* Kp = kb + (size_t)bh * 1024 * 32;
    const ushort* Vb = vx + (size_t)bh * 32768;
    const ushort* bxp = Bx + (((size_t)(h * 64 + (qbase >> 4)) * 16) * 64 + lane) * 16;
    ushort* Pw = Pl + wave * 16 * 72;

    bf16x8 qf = *(const bf16x8*)&Q[(qbase + c) * 32 + quad * 8];

    float l_[4] = {0.f, 0.f, 0.f, 0.f};
    f32x4 Of0 = {0.f, 0.f, 0.f, 0.f}, Of1 = {0.f, 0.f, 0.f, 0.f};

    for (int kb64 = z * 512; kb64 < z * 512 + 512; kb64 += 64) {
        f32x4 S[4];
        f32x4 zf = {0.f, 0.f, 0.f, 0.f};
#pragma unroll
        for (int f = 0; f < 4; ++f) {
            bf16x8 kf = *(const bf16x8*)&Kp[(kb64 + f * 16 + c) * 32 + quad * 8];
            S[f] = __builtin_amdgcn_mfma_f32_16x16x32_bf16(qf, kf, zf, 0, 0, 0);
        }
        // fragment-ordered bias: 32 B per lane, coalesced
        union { uint4 v[2]; ushort s[16]; } bu;
        const uint4* bsrc = (const uint4*)(bxp + (size_t)(kb64 >> 6) * 1024);
        bu.v[0] = bsrc[0];
        bu.v[1] = bsrc[1];
#pragma unroll
        for (int f = 0; f < 4; ++f)
#pragma unroll
            for (int r = 0; r < 4; ++r) {
                float p = __expf(S[f][r] + bf2f(bu.s[f * 4 + r]));
                S[f][r] = p;
                l_[r] += p;
            }
        // P (C-layout) -> LDS -> A-layout; per-wave slice, no barrier needed
#pragma unroll
        for (int f = 0; f < 4; ++f)
#pragma unroll
            for (int r = 0; r < 4; ++r)
                Pw[(quad * 4 + r) * 72 + f * 16 + c] = f2bf(S[f][r]);
#pragma unroll
        for (int kc = 0; kc < 2; ++kc) {
            int kca = (kb64 >> 5) + kc;
            bf16x8 pf = *(const bf16x8*)&Pw[c * 72 + kc * 32 + quad * 8];
            bf16x8 vf0 = *(const bf16x8*)&Vb[((kca * 2 + 0) * 64 + lane) * 8];
            Of0 = __builtin_amdgcn_mfma_f32_16x16x32_bf16(pf, vf0, Of0, 0, 0, 0);
            bf16x8 vf1 = *(const bf16x8*)&Vb[((kca * 2 + 1) * 64 + lane) * 8];
            Of1 = __builtin_amdgcn_mfma_f32_16x16x32_bf16(pf, vf1, Of1, 0, 0, 0);
        }
    }
#pragma unroll
    for (int r = 0; r < 4; ++r) {
        float l = l_[r];
        l += __shfl_xor(l, 1, 64);
        l += __shfl_xor(l, 2, 64);
        l += __shfl_xor(l, 4, 64);
        l += __shfl_xor(l, 8, 64);
        int qr = qbase + quad * 4 + r;
        size_t ob = (((size_t)z * 64 + bh) * 1024 + qr) * 32;
        Opart[ob + c]      = Of0[r];
        Opart[ob + 16 + c] = Of1[r];
        if (c == 0) lpart[(size_t)z * 65536 + bh * 1024 + qr] = l;
    }
}

// ---------------------------------------------------------------------------
// Kernel 6: combine key-split partials: attnout = (O0+O1)/(l0+l1), bf16,
//   written in [b][n][h*32+d] layout for the out-proj GEMM.
// ---------------------------------------------------------------------------
__global__ __launch_bounds__(256) void combine_k(const float* __restrict__ Opart,
                                                 const float* __restrict__ lpart,
                                                 ushort* __restrict__ attnout)
{
    int t = blockIdx.x * 256 + threadIdx.x;   // 262144 threads, 8 d each
    int g = t & 3;
    int qg = t >> 2;                          // bh*1024 + qr
    int bh = qg >> 10, qr = qg & 1023;
    int b = bh >> 3, h = bh & 7;
    size_t ob = ((size_t)qg) * 32 + g * 8;
    float4 o00 = *(const float4*)&Opart[ob];
    float4 o01 = *(const float4*)&Opart[ob + 4];
    float4 o10 = *(const float4*)&Opart[(size_t)64 * 1024 * 32 + ob];
    float4 o11 = *(const float4*)&Opart[(size_t)64 * 1024 * 32 + ob + 4];
    float inv = 1.f / (lpart[qg] + lpart[65536 + qg]);
    float v[8] = {(o00.x + o10.x) * inv, (o00.y + o10.y) * inv,
                  (o00.z + o10.z) * inv, (o00.w + o10.w) * inv,
                  (o01.x + o11.x) * inv, (o01.y + o11.y) * inv,
                  (o01.z + o11.z) * inv, (o01.w + o11.w) * inv};
    union { uint4 u; ushort s[8]; } o;
#pragma unroll
    for (int e = 0; e < 8; ++e) o.s[e] = f2bf(v[e]);
    *(uint4*)&attnout[(((size_t)b * 1024 + qr) * 256) + h * 32 + g * 8] = o.u;
}

// ---------------------------------------------------------------------------
extern "C" void kernel_launch(void* const* d_in, const int* in_sizes, int n_in,
                              void* d_out, int out_size, void* d_ws, size_t ws_size,
                              hipStream_t stream)
{
    const float* x    = (const float*)d_in[0];
    const float* wq   = (const float*)d_in[1];
    const float* wk   = (const float*)d_in[2];
    const float* wv   = (const float*)d_in[3];
    const float* gq   = (const float*)d_in[4];
    const float* bq   = (const float*)d_in[5];
    const float* gk   = (const float*)d_in[6];
    const float* bk   = (const float*)d_in[7];
    const float* gv   = (const float*)d_in[8];
    const float* bv   = (const float*)d_in[9];
    const float* btab = (const float*)d_in[10];
    const float* wo   = (const float*)d_in[11];
    const float* bo   = (const float*)d_in[12];
    float* out = (float*)d_out;

    char* w = (char*)d_ws;
    size_t off = 0;
    auto alloc = [&](size_t bytes) -> char* {
        char* p = w + off;
        off += (bytes + 255) & ~(size_t)255;
        return p;
    };
    ushort* Abuf    = (ushort*)alloc(8192ull * 2304 * 2);   // im2col patches (36.9 MB)
    ushort* Wbuf    = (ushort*)alloc(768ull * 2304 * 2);    // concat conv weights
    ushort* wo_bf   = (ushort*)alloc(65536ull * 2);         // out-proj weight
    ushort* Bx      = (ushort*)alloc(8192ull * 64 * 16 * 2);// bias frags (16.7 MB, DEDICATED)
    float*  P0      = (float*)alloc(8192ull * 768 * 4);     // split-K partial 0
    float*  P1      = (float*)alloc(8192ull * 768 * 4);     // split-K partial 1
    float2* part    = (float2*)alloc(48ull * 1024 * 8);     // stats partials
    float*  stats   = (float*)alloc(384);                   // [proj][b][sum,sumsq]
    float*  Opart   = (float*)alloc(2ull * 64 * 1024 * 32 * 4);   // attn O partials
    float*  lpart   = (float*)alloc(2ull * 64 * 1024 * 4);        // attn l partials
    // aliases into Abuf (dead after the conv GEMM; stream-ordered):
    ushort* qb      = (ushort*)Abuf;                        // 4 MB
    ushort* kb2     = qb  + 8ull * 8 * 1024 * 32;           // 4 MB
    ushort* vx      = kb2 + 8ull * 8 * 1024 * 32;           // 4 MB (fragment order)
    ushort* attnout = vx  + 8ull * 8 * 32 * 1024;           // 4 MB

    prep_k<<<3392, 256, 0, stream>>>(x, wq, wk, wv, wo, btab,
                                     Abuf, Wbuf, wo_bf, Bx);
    gemm_bt<<<dim3(64, 6, 2), 256, 0, stream>>>(Abuf, Wbuf, 8192, 768, 2304,
                                                P0, nullptr, nullptr, 0);
    stats1_k<<<3072, 256, 0, stream>>>(P0, P1, part);
    stats2_k<<<48, 256, 0, stream>>>(part, stats);
    gn_k<<<3072, 256, 0, stream>>>(P0, P1, stats, gq, bq, gk, bk, gv, bv,
                                   qb, kb2, vx);
    attn_k<<<dim3(16, 64, 2), 256, 0, stream>>>(qb, kb2, vx, Bx, Opart, lpart);
    combine_k<<<1024, 256, 0, stream>>>(Opart, lpart, attnout);
    gemm_bt<<<dim3(2, 64, 1), 256, 0, stream>>>(wo_bf, attnout, 256, 8192, 256,
                                                nullptr, out, bo, 1);
}

// Round 10
// 219.149 us; speedup vs baseline: 1.0780x; 1.0550x over previous
//
#include <hip/hip_runtime.h>
#include <cstdint>
#include <cstddef>

#define GEPS 1e-6f

using bf16x8 = __attribute__((ext_vector_type(8))) short;   // 8 bf16 = 4 VGPRs
using f32x4  = __attribute__((ext_vector_type(4))) float;   // MFMA C/D frag

__device__ inline ushort f2bf(float x) {
    union { float f; uint32_t u; } v; v.f = x;
    uint32_t r = (v.u + 0x7fffu + ((v.u >> 16) & 1u)) >> 16;  // RNE
    return (ushort)r;
}
__device__ inline float bf2f(ushort b) {
    union { float f; uint32_t u; } v; v.u = ((uint32_t)b) << 16;
    return v.f;
}

// async global->LDS, 16 bytes per lane. LDS dest = wave-uniform base + lane*16.
__device__ inline void gll16(const void* g, void* l) {
    __builtin_amdgcn_global_load_lds(
        (const __attribute__((address_space(1))) void*)g,
        (__attribute__((address_space(3))) void*)l, 16, 0, 0);
}

// ---------------------------------------------------------------------------
// Kernel 1: merged preprocessing (one launch). Bx has a DEDICATED region
//   (R8 lesson: never alias a buffer concurrently written in the same grid).
//   blocks 0..511     : im2col via LDS transpose (b, py, ci-half)
//   blocks 512..1279  : conv weights -> bf16, k TAP-MAJOR (k = tap*256+ci)
//   blocks 1280..1343 : wo -> bf16
//   blocks 1344..3391 : bias table -> MFMA-fragment-ordered Bx (bf16)
// ---------------------------------------------------------------------------
__global__ __launch_bounds__(256) void prep_k(
    const float* __restrict__ x,
    const float* __restrict__ wq, const float* __restrict__ wk,
    const float* __restrict__ wv, const float* __restrict__ wo,
    const float* __restrict__ btab,
    ushort* __restrict__ Ab, ushort* __restrict__ Wbuf,
    ushort* __restrict__ wo_bf, ushort* __restrict__ Bx)
{
    __shared__ __align__(16) ushort Xs[3 * 34 * 128];   // 25.5 KB (max use)
    int tid = threadIdx.x;
    int blk = blockIdx.x;

    if (blk < 512) {
        // ---- im2col ----
        int b = blk >> 6, py = (blk >> 1) & 31, half = blk & 1;
#pragma unroll
        for (int p = tid; p < 768; p += 256) {
            int yy = p >> 8;
            int q = p & 255;
            int col = (q >> 7) ? 33 : 0;
            int ci = q & 127;
            Xs[(yy * 34 + col) * 128 + ci] = 0;
        }
#pragma unroll
        for (int it = 0; it < 12; ++it) {
            int j = it * 256 + tid;
            int ci_l = j / 24;
            int o = (j - ci_l * 24) * 4;
            int yy = o >> 5, xx = o & 31;
            int row = py - 1 + yy;
            float4 v = make_float4(0.f, 0.f, 0.f, 0.f);
            if (row >= 0 && row < 32)
                v = *(const float4*)&x[((size_t)(b * 256 + half * 128 + ci_l)) * 1024 + row * 32 + xx];
            int base = (yy * 34 + xx + 1) * 128 + ci_l;
            Xs[base + 0 * 128] = f2bf(v.x);
            Xs[base + 1 * 128] = f2bf(v.y);
            Xs[base + 2 * 128] = f2bf(v.z);
            Xs[base + 3 * 128] = f2bf(v.w);
        }
        __syncthreads();
        ushort* dst = Ab + (size_t)(b * 1024 + py * 32) * 2304;
#pragma unroll
        for (int it = 0; it < 18; ++it) {
            int idx = it * 256 + tid;       // 0..4607
            int ci8l = idx & 15;
            int tp = (idx >> 4) % 9;
            int px = idx / 144;
            int kh = tp / 3, kw = tp - kh * 3;
            uint4 p = *(const uint4*)&Xs[(kh * 34 + px + kw) * 128 + ci8l * 8];
            *(uint4*)&dst[(size_t)(px * 288 + tp * 32 + half * 16 + ci8l) * 8] = p;
        }
        return;
    }
    if (blk < 1280) {
        // ---- conv weight pack (LDS transpose) ----
        int wrow = blk - 512;               // 0..767
        int proj = wrow >> 8, co = wrow & 255;
        const float* src = ((proj == 0) ? wq : ((proj == 1) ? wk : wv)) + (size_t)co * 2304;
#pragma unroll
        for (int j = 0; j < 9; ++j) {
            int idx = j * 256 + tid;
            Xs[idx] = f2bf(src[idx]);       // coalesced fp32 read
        }
        __syncthreads();
        ushort* dst = Wbuf + (size_t)wrow * 2304;
#pragma unroll
        for (int j = 0; j < 9; ++j)          // k = j*256+tid: tap=j, ci=tid
            dst[j * 256 + tid] = Xs[tid * 9 + j];   // coalesced store
        return;
    }
    if (blk < 1344) {
        // ---- wo pack ----
        int t = (blk - 1280) * 256 + tid;    // 0..16383, 4 elems each
        float4 v = *(const float4*)&wo[(size_t)t * 4];
        union { uint2 u; ushort s[4]; } o;
        o.s[0] = f2bf(v.x); o.s[1] = f2bf(v.y); o.s[2] = f2bf(v.z); o.s[3] = f2bf(v.w);
        *(uint2*)&wo_bf[(size_t)t * 4] = o.u;
        return;
    }
    // ---- Bx expansion ----
    int g = (blk - 1344) * 4 + (tid >> 6);   // tile id 0..8191
    int l = tid & 63;
    int h = g >> 10, qt = (g >> 4) & 63, kt = g & 15;
    int quad = l >> 4, c = l & 15;
    union { uint4 v[2]; ushort s[16]; } o;
#pragma unroll
    for (int f = 0; f < 4; ++f)
#pragma unroll
        for (int r = 0; r < 4; ++r) {
            int qrow = qt * 16 + quad * 4 + r;
            int key = kt * 64 + f * 16 + c;
            int dy = (qrow >> 5) - (key >> 5) + 31;
            int dx = (qrow & 31) - (key & 31) + 31;
            o.s[f * 4 + r] = f2bf(btab[(dy * 63 + dx) * 8 + h]);
        }
    uint4* dst = (uint4*)(Bx + ((size_t)g * 64 + l) * 16);
    dst[0] = o.v[0];
    dst[1] = o.v[1];
}

// ---------------------------------------------------------------------------
// Kernel 2/8: bf16 GEMM  C[M,N] = A[M,K] * B[N,K]^T, 128x128 tile, BK=64,
//   split-K via blockIdx.z, PLAIN-STORE partials.
//   mode 0 (conv): store BF16 partial to Cpart + z*M*N (traffic halved vs fp32;
//     RNE rounding error ~0.2% of partial sigma -> negligible downstream)
//   mode 1 (out-proj, gridDim.z==1): store fp32 d_out[b][o][px] = C + bias[o]
// ---------------------------------------------------------------------------
__global__ __launch_bounds__(256, 3) void gemm_bt(
    const ushort* __restrict__ A, const ushort* __restrict__ B,
    int M, int N, int K,
    ushort* __restrict__ Cpart,
    float* __restrict__ Cout, const float* __restrict__ bias, int mode)
{
    __shared__ __align__(16) ushort As[128 * 64];
    __shared__ __align__(16) ushort Bs[128 * 64];
    int tid = threadIdx.x;
    int mbase = blockIdx.x * 128, nbase = blockIdx.y * 128;
    int kspan = K / gridDim.z;
    int k0 = blockIdx.z * kspan;
    int wave = tid >> 6, lane = tid & 63;
    int wm = wave & 1, wn = wave >> 1;
    int quad = lane >> 4, c = lane & 15;

    int row_s = tid >> 3;               // 0..31 staging row within chunk
    int cc8 = (tid & 7) ^ (row_s & 7);  // swizzled global column-block
    ushort* ldsA = As + wave * 512;     // wave-uniform dest base (+lane*16B)
    ushort* ldsB = Bs + wave * 512;

    f32x4 acc[4][4];
#pragma unroll
    for (int i = 0; i < 4; ++i)
#pragma unroll
        for (int j = 0; j < 4; ++j) acc[i][j] = (f32x4){0.f, 0.f, 0.f, 0.f};

    for (int kb = k0; kb < k0 + kspan; kb += 64) {
        __syncthreads();
#pragma unroll
        for (int R = 0; R < 4; ++R) {
            int row = R * 32 + row_s;
            gll16(A + (size_t)(mbase + row) * K + kb + cc8 * 8,
                  ldsA + R * 2048);
            gll16(B + (size_t)(nbase + row) * K + kb + cc8 * 8,
                  ldsB + R * 2048);
        }
        __syncthreads();
#pragma unroll
        for (int kq = 0; kq < 2; ++kq) {
            bf16x8 af[4], bfr[4];
            int sw = ((kq * 4 + quad) ^ (c & 7)) * 8;
#pragma unroll
            for (int i = 0; i < 4; ++i) {
                af[i]  = *(const bf16x8*)&As[(wm * 64 + i * 16 + c) * 64 + sw];
                bfr[i] = *(const bf16x8*)&Bs[(wn * 64 + i * 16 + c) * 64 + sw];
            }
#pragma unroll
            for (int i = 0; i < 4; ++i)
#pragma unroll
                for (int j = 0; j < 4; ++j)
                    acc[i][j] = __builtin_amdgcn_mfma_f32_16x16x32_bf16(
                        af[i], bfr[j], acc[i][j], 0, 0, 0);
        }
    }

    if (mode == 0) {
        ushort* Cp = Cpart + (size_t)blockIdx.z * M * N;
#pragma unroll
        for (int i = 0; i < 4; ++i) {
            int mrow = mbase + wm * 64 + i * 16 + quad * 4;
#pragma unroll
            for (int j = 0; j < 4; ++j) {
                int ncol = nbase + wn * 64 + j * 16 + c;
#pragma unroll
                for (int r = 0; r < 4; ++r)
                    Cp[(size_t)(mrow + r) * N + ncol] = f2bf(acc[i][j][r]);
            }
        }
    } else {
#pragma unroll
        for (int i = 0; i < 4; ++i) {
            int mrow0 = mbase + wm * 64 + i * 16 + quad * 4;
#pragma unroll
            for (int j = 0; j < 4; ++j) {
                int ncol = nbase + wn * 64 + j * 16 + c;
                int bb = ncol >> 10, px = ncol & 1023;
#pragma unroll
                for (int r = 0; r < 4; ++r) {
                    int o = mrow0 + r;
                    Cout[((size_t)bb * 256 + o) * 1024 + px] = acc[i][j][r] + bias[o];
                }
            }
        }
    }
}

// ---------------------------------------------------------------------------
// Kernel 3: stats stage 1 — atomic-free partials over bf16 P0+P1.
// ---------------------------------------------------------------------------
__global__ __launch_bounds__(256) void stats1_k(const ushort* __restrict__ P0,
                                                const ushort* __restrict__ P1,
                                                float2* __restrict__ part)
{
    int t = blockIdx.x * 256 + threadIdx.x;     // 786432 threads x 8 elems
    size_t base = (size_t)t * 8;
    union { uint4 v; ushort s[8]; } a, b2;
    a.v  = *(const uint4*)&P0[base];
    b2.v = *(const uint4*)&P1[base];
    float s1 = 0.f, s2 = 0.f;
#pragma unroll
    for (int e = 0; e < 8; ++e) {
        float v = bf2f(a.s[e]) + bf2f(b2.s[e]);
        s1 += v; s2 += v * v;
    }
#pragma unroll
    for (int mk = 1; mk < 32; mk <<= 1) {
        s1 += __shfl_xor(s1, mk, 64);
        s2 += __shfl_xor(s2, mk, 64);
    }
    if ((threadIdx.x & 31) == 0) {
        int gg = t >> 5;                // group = one 256-elem (proj,m) segment
        int m = gg / 3;
        int proj = gg - m * 3;
        int b = m >> 10, slot = m & 1023;
        part[(proj * 8 + b) * 1024 + slot] = make_float2(s1, s2);
    }
}

// ---------------------------------------------------------------------------
// Kernel 3b: stats stage 2 — 48 blocks, each reduces 1024 float2 partials.
// ---------------------------------------------------------------------------
__global__ __launch_bounds__(256) void stats2_k(const float2* __restrict__ part,
                                                float* __restrict__ stats)
{
    __shared__ float w1[4], w2[4];
    int s = blockIdx.x, tid = threadIdx.x;
    float s1 = 0.f, s2 = 0.f;
#pragma unroll
    for (int i = 0; i < 4; ++i) {
        float2 v = part[(size_t)s * 1024 + tid * 4 + i];
        s1 += v.x; s2 += v.y;
    }
#pragma unroll
    for (int mk = 1; mk < 64; mk <<= 1) {
        s1 += __shfl_xor(s1, mk, 64);
        s2 += __shfl_xor(s2, mk, 64);
    }
    if ((tid & 63) == 0) { w1[tid >> 6] = s1; w2[tid >> 6] = s2; }
    __syncthreads();
    if (tid == 0) {
        stats[s * 2 + 0] = w1[0] + w1[1] + w1[2] + w1[3];
        stats[s * 2 + 1] = w2[0] + w2[1] + w2[2] + w2[3];
    }
}

// ---------------------------------------------------------------------------
// Kernel 4: GroupNorm(1) + exact GELU + head reshape; sums bf16 split-K
//   partials. q/k -> [b][h][n][d]; V -> fragment order Vx.
// ---------------------------------------------------------------------------
__global__ void gn_k(const ushort* __restrict__ P0, const ushort* __restrict__ P1,
                     const float* __restrict__ stats,
                     const float* __restrict__ gq, const float* __restrict__ bq,
                     const float* __restrict__ gk, const float* __restrict__ bk,
                     const float* __restrict__ gv, const float* __restrict__ bv,
                     ushort* __restrict__ qb, ushort* __restrict__ kb2,
                     ushort* __restrict__ vx)
{
    int t = blockIdx.x * 256 + threadIdx.x;     // 8192 * 96 threads
    int m = t / 96;
    int nn = (t - m * 96) * 8;
    int proj = nn >> 8, co = nn & 255;
    int b = m >> 10, px = m & 1023;
    float s1 = stats[(proj * 8 + b) * 2 + 0];
    float s2 = stats[(proj * 8 + b) * 2 + 1];
    const float Ninv = 1.f / 262144.f;
    float mu = s1 * Ninv;
    float var = fmaxf(s2 * Ninv - mu * mu, 0.f);
    float rsig = rsqrtf(var + GEPS);
    const float* gam = (proj == 0) ? gq : ((proj == 1) ? gk : gv);
    const float* bet = (proj == 0) ? bq : ((proj == 1) ? bk : bv);

    size_t base = (size_t)m * 768 + nn;
    union { uint4 v; ushort s[8]; } a, c2;
    a.v  = *(const uint4*)&P0[base];
    c2.v = *(const uint4*)&P1[base];
    union { uint4 v; ushort s[8]; } outp;
#pragma unroll
    for (int e = 0; e < 8; ++e) {
        int cc = co + e;
        float xv = bf2f(a.s[e]) + bf2f(c2.s[e]);
        float xn = (xv - mu) * rsig * gam[cc] + bet[cc];
        float ge = 0.5f * xn * (1.f + erff(xn * 0.70710678118654752f));
        outp.s[e] = f2bf(ge);
    }
    int h = co >> 5, d = co & 31;
    if (proj == 0) {
        *(uint4*)(qb + ((((size_t)b * 8 + h) * 1024 + px) * 32 + d)) = outp.v;
    } else if (proj == 1) {
        *(uint4*)(kb2 + ((((size_t)b * 8 + h) * 1024 + px) * 32 + d)) = outp.v;
    } else {
        // Vx[bh][kca=px>>5][half=d>>4][lane=quad*16+(d&15)][j=px&7]
        ushort* vb = vx + ((size_t)b * 8 + h) * 32768;
        int kca = px >> 5, quad = (px >> 3) & 3, j = px & 7;
#pragma unroll
        for (int e = 0; e < 8; ++e) {
            int dd = d + e;
            vb[(((kca * 2 + (dd >> 4)) * 64) + quad * 16 + (dd & 15)) * 8 + j] = outp.s[e];
        }
    }
}

// ---------------------------------------------------------------------------
// Kernel 5: fused attention, KEY-SPLIT z=2 (2048 blocks -> ~8 blocks/CU).
//   Writes UNNORMALIZED bf16 O partials + fp32 l partials; combine_k finishes.
// ---------------------------------------------------------------------------
__global__ __launch_bounds__(256, 8) void attn_k(
    const ushort* __restrict__ qb, const ushort* __restrict__ kb,
    const ushort* __restrict__ vx, const ushort* __restrict__ Bx,
    ushort* __restrict__ Opart, float* __restrict__ lpart)
{
    __shared__ __align__(16) ushort Pl[4 * 16 * 72];
    int tid = threadIdx.x, wave = tid >> 6, lane = tid & 63;
    int quad = lane >> 4, c = lane & 15;
    int bh = blockIdx.y;               // b*8 + h
    int h = bh & 7;
    int z = blockIdx.z;
    int qbase = blockIdx.x * 64 + wave * 16;

    const ushort* Q  = qb + (size_t)bh * 1024 * 32;
    const ushort* Kp = kb + (size_t)bh * 1024 * 32;
    const ushort* Vb = vx + (size_t)bh * 32768;
    const ushort* bxp = Bx + (((size_t)(h * 64 + (qbase >> 4)) * 16) * 64 + lane) * 16;
    ushort* Pw = Pl + wave * 16 * 72;

    bf16x8 qf = *(const bf16x8*)&Q[(qbase + c) * 32 + quad * 8];

    float l_[4] = {0.f, 0.f, 0.f, 0.f};
    f32x4 Of0 = {0.f, 0.f, 0.f, 0.f}, Of1 = {0.f, 0.f, 0.f, 0.f};

    for (int kb64 = z * 512; kb64 < z * 512 + 512; kb64 += 64) {
        f32x4 S[4];
        f32x4 zf = {0.f, 0.f, 0.f, 0.f};
#pragma unroll
        for (int f = 0; f < 4; ++f) {
            bf16x8 kf = *(const bf16x8*)&Kp[(kb64 + f * 16 + c) * 32 + quad * 8];
            S[f] = __builtin_amdgcn_mfma_f32_16x16x32_bf16(qf, kf, zf, 0, 0, 0);
        }
        // fragment-ordered bias: 32 B per lane, coalesced
        union { uint4 v[2]; ushort s[16]; } bu;
        const uint4* bsrc = (const uint4*)(bxp + (size_t)(kb64 >> 6) * 1024);
        bu.v[0] = bsrc[0];
        bu.v[1] = bsrc[1];
#pragma unroll
        for (int f = 0; f < 4; ++f)
#pragma unroll
            for (int r = 0; r < 4; ++r) {
                float p = __expf(S[f][r] + bf2f(bu.s[f * 4 + r]));
                S[f][r] = p;
                l_[r] += p;
            }
        // P (C-layout) -> LDS -> A-layout; per-wave slice, no barrier needed
#pragma unroll
        for (int f = 0; f < 4; ++f)
#pragma unroll
            for (int r = 0; r < 4; ++r)
                Pw[(quad * 4 + r) * 72 + f * 16 + c] = f2bf(S[f][r]);
#pragma unroll
        for (int kc = 0; kc < 2; ++kc) {
            int kca = (kb64 >> 5) + kc;
            bf16x8 pf = *(const bf16x8*)&Pw[c * 72 + kc * 32 + quad * 8];
            bf16x8 vf0 = *(const bf16x8*)&Vb[((kca * 2 + 0) * 64 + lane) * 8];
            Of0 = __builtin_amdgcn_mfma_f32_16x16x32_bf16(pf, vf0, Of0, 0, 0, 0);
            bf16x8 vf1 = *(const bf16x8*)&Vb[((kca * 2 + 1) * 64 + lane) * 8];
            Of1 = __builtin_amdgcn_mfma_f32_16x16x32_bf16(pf, vf1, Of1, 0, 0, 0);
        }
    }
#pragma unroll
    for (int r = 0; r < 4; ++r) {
        float l = l_[r];
        l += __shfl_xor(l, 1, 64);
        l += __shfl_xor(l, 2, 64);
        l += __shfl_xor(l, 4, 64);
        l += __shfl_xor(l, 8, 64);
        int qr = qbase + quad * 4 + r;
        size_t ob = (((size_t)z * 64 + bh) * 1024 + qr) * 32;
        Opart[ob + c]      = f2bf(Of0[r]);
        Opart[ob + 16 + c] = f2bf(Of1[r]);
        if (c == 0) lpart[(size_t)z * 65536 + bh * 1024 + qr] = l;
    }
}

// ---------------------------------------------------------------------------
// Kernel 6: combine key-split partials: attnout = (O0+O1)/(l0+l1), bf16,
//   written in [b][n][h*32+d] layout for the out-proj GEMM.
// ---------------------------------------------------------------------------
__global__ __launch_bounds__(256) void combine_k(const ushort* __restrict__ Opart,
                                                 const float* __restrict__ lpart,
                                                 ushort* __restrict__ attnout)
{
    int t = blockIdx.x * 256 + threadIdx.x;   // 262144 threads, 8 d each
    int g = t & 3;
    int qg = t >> 2;                          // bh*1024 + qr
    int bh = qg >> 10, qr = qg & 1023;
    int b = bh >> 3, h = bh & 7;
    size_t ob = ((size_t)qg) * 32 + g * 8;
    union { uint4 v; ushort s[8]; } o0, o1;
    o0.v = *(const uint4*)&Opart[ob];
    o1.v = *(const uint4*)&Opart[(size_t)64 * 1024 * 32 + ob];
    float inv = 1.f / (lpart[qg] + lpart[65536 + qg]);
    union { uint4 u; ushort s[8]; } o;
#pragma unroll
    for (int e = 0; e < 8; ++e)
        o.s[e] = f2bf((bf2f(o0.s[e]) + bf2f(o1.s[e])) * inv);
    *(uint4*)&attnout[(((size_t)b * 1024 + qr) * 256) + h * 32 + g * 8] = o.u;
}

// ---------------------------------------------------------------------------
extern "C" void kernel_launch(void* const* d_in, const int* in_sizes, int n_in,
                              void* d_out, int out_size, void* d_ws, size_t ws_size,
                              hipStream_t stream)
{
    const float* x    = (const float*)d_in[0];
    const float* wq   = (const float*)d_in[1];
    const float* wk   = (const float*)d_in[2];
    const float* wv   = (const float*)d_in[3];
    const float* gq   = (const float*)d_in[4];
    const float* bq   = (const float*)d_in[5];
    const float* gk   = (const float*)d_in[6];
    const float* bk   = (const float*)d_in[7];
    const float* gv   = (const float*)d_in[8];
    const float* bv   = (const float*)d_in[9];
    const float* btab = (const float*)d_in[10];
    const float* wo   = (const float*)d_in[11];
    const float* bo   = (const float*)d_in[12];
    float* out = (float*)d_out;

    char* w = (char*)d_ws;
    size_t off = 0;
    auto alloc = [&](size_t bytes) -> char* {
        char* p = w + off;
        off += (bytes + 255) & ~(size_t)255;
        return p;
    };
    ushort* Abuf    = (ushort*)alloc(8192ull * 2304 * 2);   // im2col patches (36.9 MB)
    ushort* Wbuf    = (ushort*)alloc(768ull * 2304 * 2);    // concat conv weights
    ushort* wo_bf   = (ushort*)alloc(65536ull * 2);         // out-proj weight
    ushort* Bx      = (ushort*)alloc(8192ull * 64 * 16 * 2);// bias frags (16.7 MB, DEDICATED)
    ushort* P0      = (ushort*)alloc(8192ull * 768 * 2);    // split-K partial 0 (bf16)
    ushort* P1      = (ushort*)alloc(8192ull * 768 * 2);    // split-K partial 1 (bf16)
    float2* part    = (float2*)alloc(48ull * 1024 * 8);     // stats partials
    float*  stats   = (float*)alloc(384);                   // [proj][b][sum,sumsq]
    ushort* Opart   = (ushort*)alloc(2ull * 64 * 1024 * 32 * 2);  // attn O partials (bf16)
    float*  lpart   = (float*)alloc(2ull * 64 * 1024 * 4);        // attn l partials
    // aliases into Abuf (dead after the conv GEMM; stream-ordered):
    ushort* qb      = (ushort*)Abuf;                        // 4 MB
    ushort* kb2     = qb  + 8ull * 8 * 1024 * 32;           // 4 MB
    ushort* vx      = kb2 + 8ull * 8 * 1024 * 32;           // 4 MB (fragment order)
    ushort* attnout = vx  + 8ull * 8 * 32 * 1024;           // 4 MB

    prep_k<<<3392, 256, 0, stream>>>(x, wq, wk, wv, wo, btab,
                                     Abuf, Wbuf, wo_bf, Bx);
    gemm_bt<<<dim3(64, 6, 2), 256, 0, stream>>>(Abuf, Wbuf, 8192, 768, 2304,
                                                P0, nullptr, nullptr, 0);
    stats1_k<<<3072, 256, 0, stream>>>(P0, P1, part);
    stats2_k<<<48, 256, 0, stream>>>(part, stats);
    gn_k<<<3072, 256, 0, stream>>>(P0, P1, stats, gq, bq, gk, bk, gv, bv,
                                   qb, kb2, vx);
    attn_k<<<dim3(16, 64, 2), 256, 0, stream>>>(qb, kb2, vx, Bx, Opart, lpart);
    combine_k<<<1024, 256, 0, stream>>>(Opart, lpart, attnout);
    gemm_bt<<<dim3(2, 64, 1), 256, 0, stream>>>(wo_bf, attnout, 256, 8192, 256,
                                                nullptr, out, bo, 1);
}